// Round 2
// baseline (1187.199 us; speedup 1.0000x reference)
//
#include <hip/hip_runtime.h>

#define IN_F 128
#define EF 16

// ---------------------------------------------------------------------------
// Edge scatter: for each edge e, atomically add H[src] row into agg[dst]
// (agg aliases d_out), edge_attr row into aggE[dst], and 1.0 into deg[dst].
// Thread layout: gid = e*128 + f. One wave covers 64 features of one edge ->
// src/dst loads wave-uniform, H gather coalesced 256B/half-wave.
// NOTE: edge_index arrives as int32 (harness passes integer inputs as int*),
// layout [2, E] flattened.
// ---------------------------------------------------------------------------
__global__ __launch_bounds__(256) void edge_scatter_kernel(
    const float* __restrict__ H,
    const int* __restrict__ ei,         // [2, E] int32
    const float* __restrict__ EA,       // [E, 16]
    float* __restrict__ agg,            // [N, 128]  (= d_out)
    float* __restrict__ aggE,           // [N, 16]
    float* __restrict__ deg,            // [N]
    int E)
{
    long long gid = (long long)blockIdx.x * 256 + threadIdx.x;
    int e = (int)(gid >> 7);
    if (e >= E) return;
    int f = (int)(gid & 127);
    int src = ei[e];
    int dst = ei[E + e];
    float m = H[(long long)src * IN_F + f];
    atomicAdd(&agg[(long long)dst * IN_F + f], m);
    if (f < EF) atomicAdd(&aggE[dst * EF + f], EA[e * EF + f]);
    if (f == 0) atomicAdd(&deg[dst], 1.0f);
}

// ---------------------------------------------------------------------------
// Node MLP, fused, IN-PLACE on agg (= d_out):
//   a   = agg + aggE @ We + deg * be     (edge MLP folded to node side)
//   h   = relu(a @ W1 + b1)
//   out = h @ W2 + b2                    (overwrites agg rows of this tile)
// One block per 32-row tile; each block reads its whole tile into LDS in
// phase 1 (before any write), so in-place is safe; blocks touch disjoint rows.
// 256 threads: thread t -> cols c4..c4+3 (c4=(t&31)*4), rows r0+{0,8,16,24}.
// ---------------------------------------------------------------------------
__global__ __launch_bounds__(256) void node_mlp_kernel(
    float* agg_out,                      // [N,128] read then overwritten (aliased, no restrict)
    const float* __restrict__ aggE,
    const float* __restrict__ deg,
    const float* __restrict__ We, const float* __restrict__ be,
    const float* __restrict__ W1, const float* __restrict__ b1,
    const float* __restrict__ W2, const float* __restrict__ b2,
    int N)
{
    __shared__ float sA[32][IN_F];
    __shared__ float sH[32][IN_F];
    const int t  = threadIdx.x;
    const int c4 = (t & 31) * 4;
    const int r0 = t >> 5;               // 0..7

    const int tile = blockIdx.x * 32;
    if (tile >= N) return;
    int rows = N - tile;
    if (rows > 32) rows = 32;

    // ---- phase 1: a = agg + aggE@We + deg*be  -> sA ----
    {
        const float4 bev = *(const float4*)&be[c4];
        #pragma unroll
        for (int i = 0; i < 4; i++) {
            int rr = r0 + 8 * i;
            float4 v = make_float4(0.f, 0.f, 0.f, 0.f);
            if (rr < rows) {
                long long r = tile + rr;
                v = *(const float4*)&agg_out[r * IN_F + c4];
                float d = deg[r];
                v.x += d * bev.x; v.y += d * bev.y; v.z += d * bev.z; v.w += d * bev.w;
                #pragma unroll
                for (int k = 0; k < EF; k++) {
                    float a = aggE[r * EF + k];
                    float4 w = *(const float4*)&We[k * IN_F + c4];
                    v.x += a * w.x; v.y += a * w.y; v.z += a * w.z; v.w += a * w.w;
                }
            }
            *(float4*)&sA[rr][c4] = v;
        }
    }
    __syncthreads();

    // ---- phase 2: h = relu(sA @ W1 + b1) -> sH ----
    {
        const float4 bv = *(const float4*)&b1[c4];
        float4 a0 = bv, a1 = bv, a2 = bv, a3 = bv;
        for (int k = 0; k < IN_F; k++) {
            float4 w = *(const float4*)&W1[k * IN_F + c4];
            float x0 = sA[r0][k];
            float x1 = sA[r0 + 8][k];
            float x2 = sA[r0 + 16][k];
            float x3 = sA[r0 + 24][k];
            a0.x += x0 * w.x; a0.y += x0 * w.y; a0.z += x0 * w.z; a0.w += x0 * w.w;
            a1.x += x1 * w.x; a1.y += x1 * w.y; a1.z += x1 * w.z; a1.w += x1 * w.w;
            a2.x += x2 * w.x; a2.y += x2 * w.y; a2.z += x2 * w.z; a2.w += x2 * w.w;
            a3.x += x3 * w.x; a3.y += x3 * w.y; a3.z += x3 * w.z; a3.w += x3 * w.w;
        }
        a0.x = fmaxf(a0.x, 0.f); a0.y = fmaxf(a0.y, 0.f); a0.z = fmaxf(a0.z, 0.f); a0.w = fmaxf(a0.w, 0.f);
        a1.x = fmaxf(a1.x, 0.f); a1.y = fmaxf(a1.y, 0.f); a1.z = fmaxf(a1.z, 0.f); a1.w = fmaxf(a1.w, 0.f);
        a2.x = fmaxf(a2.x, 0.f); a2.y = fmaxf(a2.y, 0.f); a2.z = fmaxf(a2.z, 0.f); a2.w = fmaxf(a2.w, 0.f);
        a3.x = fmaxf(a3.x, 0.f); a3.y = fmaxf(a3.y, 0.f); a3.z = fmaxf(a3.z, 0.f); a3.w = fmaxf(a3.w, 0.f);
        *(float4*)&sH[r0][c4]      = a0;
        *(float4*)&sH[r0 + 8][c4]  = a1;
        *(float4*)&sH[r0 + 16][c4] = a2;
        *(float4*)&sH[r0 + 24][c4] = a3;
    }
    __syncthreads();

    // ---- phase 3: out = sH @ W2 + b2 (overwrite agg rows) ----
    {
        const float4 bv = *(const float4*)&b2[c4];
        float4 a0 = bv, a1 = bv, a2 = bv, a3 = bv;
        for (int k = 0; k < IN_F; k++) {
            float4 w = *(const float4*)&W2[k * IN_F + c4];
            float x0 = sH[r0][k];
            float x1 = sH[r0 + 8][k];
            float x2 = sH[r0 + 16][k];
            float x3 = sH[r0 + 24][k];
            a0.x += x0 * w.x; a0.y += x0 * w.y; a0.z += x0 * w.z; a0.w += x0 * w.w;
            a1.x += x1 * w.x; a1.y += x1 * w.y; a1.z += x1 * w.z; a1.w += x1 * w.w;
            a2.x += x2 * w.x; a2.y += x2 * w.y; a2.z += x2 * w.z; a2.w += x2 * w.w;
            a3.x += x3 * w.x; a3.y += x3 * w.y; a3.z += x3 * w.z; a3.w += x3 * w.w;
        }
        #pragma unroll
        for (int i = 0; i < 4; i++) {
            int rr = r0 + 8 * i;
            if (rr < rows) {
                float4 v = (i == 0) ? a0 : (i == 1) ? a1 : (i == 2) ? a2 : a3;
                *(float4*)&agg_out[(long long)(tile + rr) * IN_F + c4] = v;
            }
        }
    }
}

extern "C" void kernel_launch(void* const* d_in, const int* in_sizes, int n_in,
                              void* d_out, int out_size, void* d_ws, size_t ws_size,
                              hipStream_t stream) {
    const float* H  = (const float*)d_in[0];
    const int*   ei = (const int*)d_in[1];     // int32 on device (harness convention)
    const float* EA = (const float*)d_in[2];
    const float* We = (const float*)d_in[3];
    const float* be = (const float*)d_in[4];
    const float* W1 = (const float*)d_in[5];
    const float* b1 = (const float*)d_in[6];
    const float* W2 = (const float*)d_in[7];
    const float* b2 = (const float*)d_in[8];
    float* out = (float*)d_out;

    const int N = in_sizes[0] / IN_F;
    const int E = in_sizes[2] / EF;

    // agg accumulator lives in d_out (N*128 floats). ws holds aggE + deg only.
    float* aggE = (float*)d_ws;                // N*16
    float* deg  = aggE + (size_t)N * EF;       // N

    hipMemsetAsync(d_out, 0, (size_t)N * IN_F * sizeof(float), stream);
    hipMemsetAsync(d_ws, 0, (size_t)N * (EF + 1) * sizeof(float), stream);

    long long tot = (long long)E * IN_F;
    int eblocks = (int)((tot + 255) / 256);
    edge_scatter_kernel<<<eblocks, 256, 0, stream>>>(H, ei, EA, out, aggE, deg, E);

    int nblocks = (N + 31) / 32;
    node_mlp_kernel<<<nblocks, 256, 0, stream>>>(out, aggE, deg, We, be, W1, b1, W2, b2, N);
}

// Round 3
// 766.121 us; speedup vs baseline: 1.5496x; 1.5496x over previous
//
#include <hip/hip_runtime.h>

#define IN_F 128
#define EF 16

// ============================ CSR-build path ================================

// 1) histogram of dst
__global__ __launch_bounds__(256) void hist_kernel(
    const int* __restrict__ ei, int* __restrict__ counts, int E)
{
    int e = blockIdx.x * 256 + threadIdx.x;
    if (e >= E) return;
    atomicAdd(&counts[ei[E + e]], 1);
}

// 2) exclusive scan, 3 kernels. chunk = 1024 elems/block.
__global__ __launch_bounds__(256) void scan_blocks_kernel(
    const int* __restrict__ in, int* __restrict__ out,
    int* __restrict__ partials, int n)
{
    __shared__ int sdata[256];
    const int t = threadIdx.x;
    const int idx0 = blockIdx.x * 1024 + t * 4;
    int v[4];
    #pragma unroll
    for (int i = 0; i < 4; i++) { int idx = idx0 + i; v[i] = (idx < n) ? in[idx] : 0; }
    int s = v[0] + v[1] + v[2] + v[3];
    sdata[t] = s;
    __syncthreads();
    // Hillis-Steele inclusive scan over 256 thread-sums
    for (int off = 1; off < 256; off <<= 1) {
        int x = (t >= off) ? sdata[t - off] : 0;
        __syncthreads();
        sdata[t] += x;
        __syncthreads();
    }
    if (t == 255) partials[blockIdx.x] = sdata[255];
    int run = (t > 0) ? sdata[t - 1] : 0;   // exclusive base for this thread
    #pragma unroll
    for (int i = 0; i < 4; i++) {
        int idx = idx0 + i;
        if (idx < n) out[idx] = run;
        run += v[i];
    }
}

__global__ void scan_partials_kernel(int* partials, int B)
{
    __shared__ int sdata[1024];
    const int t = threadIdx.x;          // blockDim = 1024
    sdata[t] = (t < B) ? partials[t] : 0;
    __syncthreads();
    for (int off = 1; off < 1024; off <<= 1) {
        int x = (t >= off) ? sdata[t - off] : 0;
        __syncthreads();
        sdata[t] += x;
        __syncthreads();
    }
    if (t < B) partials[t] = (t > 0) ? sdata[t - 1] : 0;  // exclusive
}

__global__ __launch_bounds__(256) void scan_add_kernel(
    int* __restrict__ out, const int* __restrict__ partials, int n)
{
    int idx = blockIdx.x * 256 + threadIdx.x;
    if (idx < n) out[idx] += partials[idx >> 10];
}

// 3) scatter edges into CSR order: sorted[pos] = (src, eid)
__global__ __launch_bounds__(256) void build_kernel(
    const int* __restrict__ ei, int2* __restrict__ sorted,
    const int* __restrict__ offsets, int* __restrict__ cursor, int E)
{
    int e = blockIdx.x * 256 + threadIdx.x;
    if (e >= E) return;
    int src = ei[e];
    int dst = ei[E + e];
    int pos = offsets[dst] + atomicAdd(&cursor[dst], 1);
    sorted[pos] = make_int2(src, e);
}

// 4) gather: one wave per node. lane f accumulates features f and f+64 of
// sum_{edges} H[src]; lanes 0..15 accumulate aggE; lane 0 writes deg.
// No atomics; agg written exactly once (into d_out).
__global__ __launch_bounds__(256) void gather_kernel(
    const float* __restrict__ H,
    const float* __restrict__ EA,
    const int2* __restrict__ sorted,
    const int* __restrict__ offsets,
    float* __restrict__ agg,            // [N,128] = d_out
    float* __restrict__ aggE,           // [N,16]
    float* __restrict__ degf,           // [N]
    int N)
{
    int n = blockIdx.x * 4 + (threadIdx.x >> 6);
    if (n >= N) return;
    int lane = threadIdx.x & 63;
    int s = offsets[n];
    int e_end = offsets[n + 1];
    float acc0 = 0.f, acc1 = 0.f, accE = 0.f;
    for (int i = s; i < e_end; i++) {
        int2 se = sorted[i];                       // broadcast (all lanes same addr)
        const float* hrow = H + (long long)se.x * IN_F;
        acc0 += hrow[lane];
        acc1 += hrow[lane + 64];
        if (lane < EF) accE += EA[(long long)se.y * EF + lane];
    }
    agg[(long long)n * IN_F + lane]      = acc0;
    agg[(long long)n * IN_F + 64 + lane] = acc1;
    if (lane < EF) aggE[n * EF + lane] = accE;
    if (lane == 0) degf[n] = (float)(e_end - s);
}

// ======================= fallback: atomic scatter ===========================
__global__ __launch_bounds__(256) void edge_scatter_kernel(
    const float* __restrict__ H,
    const int* __restrict__ ei,
    const float* __restrict__ EA,
    float* __restrict__ agg,
    float* __restrict__ aggE,
    float* __restrict__ deg,
    int E)
{
    long long gid = (long long)blockIdx.x * 256 + threadIdx.x;
    int e = (int)(gid >> 7);
    if (e >= E) return;
    int f = (int)(gid & 127);
    int src = ei[e];
    int dst = ei[E + e];
    float m = H[(long long)src * IN_F + f];
    atomicAdd(&agg[(long long)dst * IN_F + f], m);
    if (f < EF) atomicAdd(&aggE[dst * EF + f], EA[e * EF + f]);
    if (f == 0) atomicAdd(&deg[dst], 1.0f);
}

// ============================== node MLP ====================================
//   a   = agg + aggE @ We + deg * be
//   h   = relu(a @ W1 + b1)
//   out = h @ W2 + b2         (in-place on agg = d_out; tile fully read first)
__global__ __launch_bounds__(256) void node_mlp_kernel(
    float* agg_out,
    const float* __restrict__ aggE,
    const float* __restrict__ degf,
    const float* __restrict__ We, const float* __restrict__ be,
    const float* __restrict__ W1, const float* __restrict__ b1,
    const float* __restrict__ W2, const float* __restrict__ b2,
    int N)
{
    __shared__ float sA[32][IN_F];
    __shared__ float sH[32][IN_F];
    const int t  = threadIdx.x;
    const int c4 = (t & 31) * 4;
    const int r0 = t >> 5;

    const int tile = blockIdx.x * 32;
    if (tile >= N) return;
    int rows = N - tile;
    if (rows > 32) rows = 32;

    // phase 1
    {
        const float4 bev = *(const float4*)&be[c4];
        #pragma unroll
        for (int i = 0; i < 4; i++) {
            int rr = r0 + 8 * i;
            float4 v = make_float4(0.f, 0.f, 0.f, 0.f);
            if (rr < rows) {
                long long r = tile + rr;
                v = *(const float4*)&agg_out[r * IN_F + c4];
                float d = degf[r];
                v.x += d * bev.x; v.y += d * bev.y; v.z += d * bev.z; v.w += d * bev.w;
                #pragma unroll
                for (int k = 0; k < EF; k++) {
                    float a = aggE[r * EF + k];
                    float4 w = *(const float4*)&We[k * IN_F + c4];
                    v.x += a * w.x; v.y += a * w.y; v.z += a * w.z; v.w += a * w.w;
                }
            }
            *(float4*)&sA[rr][c4] = v;
        }
    }
    __syncthreads();

    // phase 2
    {
        const float4 bv = *(const float4*)&b1[c4];
        float4 a0 = bv, a1 = bv, a2 = bv, a3 = bv;
        for (int k = 0; k < IN_F; k++) {
            float4 w = *(const float4*)&W1[k * IN_F + c4];
            float x0 = sA[r0][k];
            float x1 = sA[r0 + 8][k];
            float x2 = sA[r0 + 16][k];
            float x3 = sA[r0 + 24][k];
            a0.x += x0 * w.x; a0.y += x0 * w.y; a0.z += x0 * w.z; a0.w += x0 * w.w;
            a1.x += x1 * w.x; a1.y += x1 * w.y; a1.z += x1 * w.z; a1.w += x1 * w.w;
            a2.x += x2 * w.x; a2.y += x2 * w.y; a2.z += x2 * w.z; a2.w += x2 * w.w;
            a3.x += x3 * w.x; a3.y += x3 * w.y; a3.z += x3 * w.z; a3.w += x3 * w.w;
        }
        a0.x = fmaxf(a0.x, 0.f); a0.y = fmaxf(a0.y, 0.f); a0.z = fmaxf(a0.z, 0.f); a0.w = fmaxf(a0.w, 0.f);
        a1.x = fmaxf(a1.x, 0.f); a1.y = fmaxf(a1.y, 0.f); a1.z = fmaxf(a1.z, 0.f); a1.w = fmaxf(a1.w, 0.f);
        a2.x = fmaxf(a2.x, 0.f); a2.y = fmaxf(a2.y, 0.f); a2.z = fmaxf(a2.z, 0.f); a2.w = fmaxf(a2.w, 0.f);
        a3.x = fmaxf(a3.x, 0.f); a3.y = fmaxf(a3.y, 0.f); a3.z = fmaxf(a3.z, 0.f); a3.w = fmaxf(a3.w, 0.f);
        *(float4*)&sH[r0][c4]      = a0;
        *(float4*)&sH[r0 + 8][c4]  = a1;
        *(float4*)&sH[r0 + 16][c4] = a2;
        *(float4*)&sH[r0 + 24][c4] = a3;
    }
    __syncthreads();

    // phase 3
    {
        const float4 bv = *(const float4*)&b2[c4];
        float4 a0 = bv, a1 = bv, a2 = bv, a3 = bv;
        for (int k = 0; k < IN_F; k++) {
            float4 w = *(const float4*)&W2[k * IN_F + c4];
            float x0 = sH[r0][k];
            float x1 = sH[r0 + 8][k];
            float x2 = sH[r0 + 16][k];
            float x3 = sH[r0 + 24][k];
            a0.x += x0 * w.x; a0.y += x0 * w.y; a0.z += x0 * w.z; a0.w += x0 * w.w;
            a1.x += x1 * w.x; a1.y += x1 * w.y; a1.z += x1 * w.z; a1.w += x1 * w.w;
            a2.x += x2 * w.x; a2.y += x2 * w.y; a2.z += x2 * w.z; a2.w += x2 * w.w;
            a3.x += x3 * w.x; a3.y += x3 * w.y; a3.z += x3 * w.z; a3.w += x3 * w.w;
        }
        #pragma unroll
        for (int i = 0; i < 4; i++) {
            int rr = r0 + 8 * i;
            if (rr < rows) {
                float4 v = (i == 0) ? a0 : (i == 1) ? a1 : (i == 2) ? a2 : a3;
                *(float4*)&agg_out[(long long)(tile + rr) * IN_F + c4] = v;
            }
        }
    }
}

// ================================ host ======================================
extern "C" void kernel_launch(void* const* d_in, const int* in_sizes, int n_in,
                              void* d_out, int out_size, void* d_ws, size_t ws_size,
                              hipStream_t stream) {
    const float* H  = (const float*)d_in[0];
    const int*   ei = (const int*)d_in[1];     // int32 [2,E]
    const float* EA = (const float*)d_in[2];
    const float* We = (const float*)d_in[3];
    const float* be = (const float*)d_in[4];
    const float* W1 = (const float*)d_in[5];
    const float* b1 = (const float*)d_in[6];
    const float* W2 = (const float*)d_in[7];
    const float* b2 = (const float*)d_in[8];
    float* out = (float*)d_out;

    const int N = in_sizes[0] / IN_F;
    const int E = in_sizes[2] / EF;

    // ---- main-path workspace layout ----
    char* p = (char*)d_ws;
    auto alloc = [&](size_t bytes) { char* r = p; p += (bytes + 255) & ~(size_t)255; return r; };
    int2*  sorted   = (int2*)alloc((size_t)E * sizeof(int2));
    float* aggE     = (float*)alloc((size_t)N * EF * sizeof(float));
    float* degf     = (float*)alloc((size_t)N * sizeof(float));
    int*   counts   = (int*)alloc((size_t)(N + 1) * sizeof(int));
    int*   offsets  = (int*)alloc((size_t)(N + 1) * sizeof(int));
    int*   cursor   = (int*)alloc((size_t)N * sizeof(int));
    int*   partials = (int*)alloc(1024 * sizeof(int));
    size_t need = (size_t)(p - (char*)d_ws);

    const int n_scan = N + 1;
    const int B = (n_scan + 1023) / 1024;   // scan chunks (98 for N=100000)

    if (ws_size >= need && B <= 1024) {
        // ---- CSR build + gather path (no float atomics) ----
        hipMemsetAsync(counts, 0, (size_t)(N + 1) * sizeof(int), stream);
        hipMemsetAsync(cursor, 0, (size_t)N * sizeof(int), stream);
        hist_kernel<<<(E + 255) / 256, 256, 0, stream>>>(ei, counts, E);
        scan_blocks_kernel<<<B, 256, 0, stream>>>(counts, offsets, partials, n_scan);
        scan_partials_kernel<<<1, 1024, 0, stream>>>(partials, B);
        scan_add_kernel<<<(n_scan + 255) / 256, 256, 0, stream>>>(offsets, partials, n_scan);
        build_kernel<<<(E + 255) / 256, 256, 0, stream>>>(ei, sorted, offsets, cursor, E);
        gather_kernel<<<(N + 3) / 4, 256, 0, stream>>>(H, EA, sorted, offsets, out, aggE, degf, N);
    } else {
        // ---- fallback: round-2 atomic scatter (small ws) ----
        float* f_aggE = (float*)d_ws;
        float* f_deg  = f_aggE + (size_t)N * EF;
        aggE = f_aggE; degf = f_deg;
        hipMemsetAsync(d_out, 0, (size_t)N * IN_F * sizeof(float), stream);
        hipMemsetAsync(d_ws, 0, (size_t)N * (EF + 1) * sizeof(float), stream);
        long long tot = (long long)E * IN_F;
        edge_scatter_kernel<<<(int)((tot + 255) / 256), 256, 0, stream>>>(H, ei, EA, out, f_aggE, f_deg, E);
    }

    node_mlp_kernel<<<(N + 31) / 32, 256, 0, stream>>>(out, aggE, degf, We, be, W1, b1, W2, b2, N);
}

// Round 4
// 645.610 us; speedup vs baseline: 1.8389x; 1.1867x over previous
//
#include <hip/hip_runtime.h>

#define IN_F 128
#define EF 16

// ============================ CSR-build path ================================

// 1) histogram of dst
__global__ __launch_bounds__(256) void hist_kernel(
    const int* __restrict__ ei, int* __restrict__ counts, int E)
{
    int e = blockIdx.x * 256 + threadIdx.x;
    if (e >= E) return;
    atomicAdd(&counts[ei[E + e]], 1);
}

// 2) exclusive scan, 3 kernels. chunk = 1024 elems/block.
__global__ __launch_bounds__(256) void scan_blocks_kernel(
    const int* __restrict__ in, int* __restrict__ out,
    int* __restrict__ partials, int n)
{
    __shared__ int sdata[256];
    const int t = threadIdx.x;
    const int idx0 = blockIdx.x * 1024 + t * 4;
    int v[4];
    #pragma unroll
    for (int i = 0; i < 4; i++) { int idx = idx0 + i; v[i] = (idx < n) ? in[idx] : 0; }
    int s = v[0] + v[1] + v[2] + v[3];
    sdata[t] = s;
    __syncthreads();
    for (int off = 1; off < 256; off <<= 1) {
        int x = (t >= off) ? sdata[t - off] : 0;
        __syncthreads();
        sdata[t] += x;
        __syncthreads();
    }
    if (t == 255) partials[blockIdx.x] = sdata[255];
    int run = (t > 0) ? sdata[t - 1] : 0;
    #pragma unroll
    for (int i = 0; i < 4; i++) {
        int idx = idx0 + i;
        if (idx < n) out[idx] = run;
        run += v[i];
    }
}

__global__ void scan_partials_kernel(int* partials, int B)
{
    __shared__ int sdata[1024];
    const int t = threadIdx.x;          // blockDim = 1024
    sdata[t] = (t < B) ? partials[t] : 0;
    __syncthreads();
    for (int off = 1; off < 1024; off <<= 1) {
        int x = (t >= off) ? sdata[t - off] : 0;
        __syncthreads();
        sdata[t] += x;
        __syncthreads();
    }
    if (t < B) partials[t] = (t > 0) ? sdata[t - 1] : 0;
}

__global__ __launch_bounds__(256) void scan_add_kernel(
    int* __restrict__ out, const int* __restrict__ partials, int n)
{
    int idx = blockIdx.x * 256 + threadIdx.x;
    if (idx < n) out[idx] += partials[idx >> 10];
}

// 3) scatter edges into CSR order: sorted[pos] = (src, eid)
__global__ __launch_bounds__(256) void build_kernel(
    const int* __restrict__ ei, int2* __restrict__ sorted,
    const int* __restrict__ offsets, int* __restrict__ cursor, int E)
{
    int e = blockIdx.x * 256 + threadIdx.x;
    if (e >= E) return;
    int src = ei[e];
    int dst = ei[E + e];
    int pos = offsets[dst] + atomicAdd(&cursor[dst], 1);
    sorted[pos] = make_int2(src, e);
}

// 4) gather: one wave per node. lane covers floats [2*lane, 2*lane+1] of the
// 128-float row (float2: one dwordx2 per edge per lane). Unroll-by-4 batches
// the sorted[] loads then the H/EA loads -> ~8 independent loads in flight
// per wave (vs 2 in the serial version) to hide L2-miss latency.
__global__ __launch_bounds__(256) void gather_kernel(
    const float* __restrict__ H,
    const float* __restrict__ EA,
    const int2* __restrict__ sorted,
    const int* __restrict__ offsets,
    float* __restrict__ agg,            // [N,128] = d_out
    float* __restrict__ aggE,           // [N,16]
    float* __restrict__ degf,           // [N]
    int N)
{
    int n = blockIdx.x * 4 + (threadIdx.x >> 6);
    if (n >= N) return;
    int lane = threadIdx.x & 63;
    int s = offsets[n];
    int e_end = offsets[n + 1];
    float2 acc = make_float2(0.f, 0.f);
    float accE = 0.f;
    int i = s;
    for (; i + 4 <= e_end; i += 4) {
        int2 s0 = sorted[i + 0];
        int2 s1 = sorted[i + 1];
        int2 s2 = sorted[i + 2];
        int2 s3 = sorted[i + 3];
        float2 v0 = *(const float2*)(H + (long long)s0.x * IN_F + lane * 2);
        float2 v1 = *(const float2*)(H + (long long)s1.x * IN_F + lane * 2);
        float2 v2 = *(const float2*)(H + (long long)s2.x * IN_F + lane * 2);
        float2 v3 = *(const float2*)(H + (long long)s3.x * IN_F + lane * 2);
        float e0 = 0.f, e1 = 0.f, e2 = 0.f, e3 = 0.f;
        if (lane < EF) {
            e0 = EA[(long long)s0.y * EF + lane];
            e1 = EA[(long long)s1.y * EF + lane];
            e2 = EA[(long long)s2.y * EF + lane];
            e3 = EA[(long long)s3.y * EF + lane];
        }
        acc.x += (v0.x + v1.x) + (v2.x + v3.x);
        acc.y += (v0.y + v1.y) + (v2.y + v3.y);
        accE  += (e0 + e1) + (e2 + e3);
    }
    for (; i < e_end; i++) {
        int2 se = sorted[i];
        float2 v = *(const float2*)(H + (long long)se.x * IN_F + lane * 2);
        acc.x += v.x; acc.y += v.y;
        if (lane < EF) accE += EA[(long long)se.y * EF + lane];
    }
    *(float2*)(agg + (long long)n * IN_F + lane * 2) = acc;
    if (lane < EF) aggE[n * EF + lane] = accE;
    if (lane == 0) degf[n] = (float)(e_end - s);
}

// ======================= fallback: atomic scatter ===========================
__global__ __launch_bounds__(256) void edge_scatter_kernel(
    const float* __restrict__ H,
    const int* __restrict__ ei,
    const float* __restrict__ EA,
    float* __restrict__ agg,
    float* __restrict__ aggE,
    float* __restrict__ deg,
    int E)
{
    long long gid = (long long)blockIdx.x * 256 + threadIdx.x;
    int e = (int)(gid >> 7);
    if (e >= E) return;
    int f = (int)(gid & 127);
    int src = ei[e];
    int dst = ei[E + e];
    float m = H[(long long)src * IN_F + f];
    atomicAdd(&agg[(long long)dst * IN_F + f], m);
    if (f < EF) atomicAdd(&aggE[dst * EF + f], EA[e * EF + f]);
    if (f == 0) atomicAdd(&deg[dst], 1.0f);
}

// ============================== node MLP ====================================
//   a   = agg + aggE @ We + deg * be
//   h   = relu(a @ W1 + b1)
//   out = h @ W2 + b2         (in-place on agg = d_out; tile fully read first)
__global__ __launch_bounds__(256) void node_mlp_kernel(
    float* agg_out,
    const float* __restrict__ aggE,
    const float* __restrict__ degf,
    const float* __restrict__ We, const float* __restrict__ be,
    const float* __restrict__ W1, const float* __restrict__ b1,
    const float* __restrict__ W2, const float* __restrict__ b2,
    int N)
{
    __shared__ float sA[32][IN_F];
    __shared__ float sH[32][IN_F];
    const int t  = threadIdx.x;
    const int c4 = (t & 31) * 4;
    const int r0 = t >> 5;

    const int tile = blockIdx.x * 32;
    if (tile >= N) return;
    int rows = N - tile;
    if (rows > 32) rows = 32;

    // phase 1
    {
        const float4 bev = *(const float4*)&be[c4];
        #pragma unroll
        for (int i = 0; i < 4; i++) {
            int rr = r0 + 8 * i;
            float4 v = make_float4(0.f, 0.f, 0.f, 0.f);
            if (rr < rows) {
                long long r = tile + rr;
                v = *(const float4*)&agg_out[r * IN_F + c4];
                float d = degf[r];
                v.x += d * bev.x; v.y += d * bev.y; v.z += d * bev.z; v.w += d * bev.w;
                #pragma unroll
                for (int k = 0; k < EF; k++) {
                    float a = aggE[r * EF + k];
                    float4 w = *(const float4*)&We[k * IN_F + c4];
                    v.x += a * w.x; v.y += a * w.y; v.z += a * w.z; v.w += a * w.w;
                }
            }
            *(float4*)&sA[rr][c4] = v;
        }
    }
    __syncthreads();

    // phase 2
    {
        const float4 bv = *(const float4*)&b1[c4];
        float4 a0 = bv, a1 = bv, a2 = bv, a3 = bv;
        for (int k = 0; k < IN_F; k++) {
            float4 w = *(const float4*)&W1[k * IN_F + c4];
            float x0 = sA[r0][k];
            float x1 = sA[r0 + 8][k];
            float x2 = sA[r0 + 16][k];
            float x3 = sA[r0 + 24][k];
            a0.x += x0 * w.x; a0.y += x0 * w.y; a0.z += x0 * w.z; a0.w += x0 * w.w;
            a1.x += x1 * w.x; a1.y += x1 * w.y; a1.z += x1 * w.z; a1.w += x1 * w.w;
            a2.x += x2 * w.x; a2.y += x2 * w.y; a2.z += x2 * w.z; a2.w += x2 * w.w;
            a3.x += x3 * w.x; a3.y += x3 * w.y; a3.z += x3 * w.z; a3.w += x3 * w.w;
        }
        a0.x = fmaxf(a0.x, 0.f); a0.y = fmaxf(a0.y, 0.f); a0.z = fmaxf(a0.z, 0.f); a0.w = fmaxf(a0.w, 0.f);
        a1.x = fmaxf(a1.x, 0.f); a1.y = fmaxf(a1.y, 0.f); a1.z = fmaxf(a1.z, 0.f); a1.w = fmaxf(a1.w, 0.f);
        a2.x = fmaxf(a2.x, 0.f); a2.y = fmaxf(a2.y, 0.f); a2.z = fmaxf(a2.z, 0.f); a2.w = fmaxf(a2.w, 0.f);
        a3.x = fmaxf(a3.x, 0.f); a3.y = fmaxf(a3.y, 0.f); a3.z = fmaxf(a3.z, 0.f); a3.w = fmaxf(a3.w, 0.f);
        *(float4*)&sH[r0][c4]      = a0;
        *(float4*)&sH[r0 + 8][c4]  = a1;
        *(float4*)&sH[r0 + 16][c4] = a2;
        *(float4*)&sH[r0 + 24][c4] = a3;
    }
    __syncthreads();

    // phase 3
    {
        const float4 bv = *(const float4*)&b2[c4];
        float4 a0 = bv, a1 = bv, a2 = bv, a3 = bv;
        for (int k = 0; k < IN_F; k++) {
            float4 w = *(const float4*)&W2[k * IN_F + c4];
            float x0 = sH[r0][k];
            float x1 = sH[r0 + 8][k];
            float x2 = sH[r0 + 16][k];
            float x3 = sH[r0 + 24][k];
            a0.x += x0 * w.x; a0.y += x0 * w.y; a0.z += x0 * w.z; a0.w += x0 * w.w;
            a1.x += x1 * w.x; a1.y += x1 * w.y; a1.z += x1 * w.z; a1.w += x1 * w.w;
            a2.x += x2 * w.x; a2.y += x2 * w.y; a2.z += x2 * w.z; a2.w += x2 * w.w;
            a3.x += x3 * w.x; a3.y += x3 * w.y; a3.z += x3 * w.z; a3.w += x3 * w.w;
        }
        #pragma unroll
        for (int i = 0; i < 4; i++) {
            int rr = r0 + 8 * i;
            if (rr < rows) {
                float4 v = (i == 0) ? a0 : (i == 1) ? a1 : (i == 2) ? a2 : a3;
                *(float4*)&agg_out[(long long)(tile + rr) * IN_F + c4] = v;
            }
        }
    }
}

// ================================ host ======================================
extern "C" void kernel_launch(void* const* d_in, const int* in_sizes, int n_in,
                              void* d_out, int out_size, void* d_ws, size_t ws_size,
                              hipStream_t stream) {
    const float* H  = (const float*)d_in[0];
    const int*   ei = (const int*)d_in[1];     // int32 [2,E]
    const float* EA = (const float*)d_in[2];
    const float* We = (const float*)d_in[3];
    const float* be = (const float*)d_in[4];
    const float* W1 = (const float*)d_in[5];
    const float* b1 = (const float*)d_in[6];
    const float* W2 = (const float*)d_in[7];
    const float* b2 = (const float*)d_in[8];
    float* out = (float*)d_out;

    const int N = in_sizes[0] / IN_F;
    const int E = in_sizes[2] / EF;

    char* p = (char*)d_ws;
    auto alloc = [&](size_t bytes) { char* r = p; p += (bytes + 255) & ~(size_t)255; return r; };
    int2*  sorted   = (int2*)alloc((size_t)E * sizeof(int2));
    float* aggE     = (float*)alloc((size_t)N * EF * sizeof(float));
    float* degf     = (float*)alloc((size_t)N * sizeof(float));
    int*   counts   = (int*)alloc((size_t)(N + 1) * sizeof(int));
    int*   offsets  = (int*)alloc((size_t)(N + 1) * sizeof(int));
    int*   cursor   = (int*)alloc((size_t)N * sizeof(int));
    int*   partials = (int*)alloc(1024 * sizeof(int));
    size_t need = (size_t)(p - (char*)d_ws);

    const int n_scan = N + 1;
    const int B = (n_scan + 1023) / 1024;

    if (ws_size >= need && B <= 1024) {
        hipMemsetAsync(counts, 0, (size_t)(N + 1) * sizeof(int), stream);
        hipMemsetAsync(cursor, 0, (size_t)N * sizeof(int), stream);
        hist_kernel<<<(E + 255) / 256, 256, 0, stream>>>(ei, counts, E);
        scan_blocks_kernel<<<B, 256, 0, stream>>>(counts, offsets, partials, n_scan);
        scan_partials_kernel<<<1, 1024, 0, stream>>>(partials, B);
        scan_add_kernel<<<(n_scan + 255) / 256, 256, 0, stream>>>(offsets, partials, n_scan);
        build_kernel<<<(E + 255) / 256, 256, 0, stream>>>(ei, sorted, offsets, cursor, E);
        gather_kernel<<<(N + 3) / 4, 256, 0, stream>>>(H, EA, sorted, offsets, out, aggE, degf, N);
    } else {
        float* f_aggE = (float*)d_ws;
        float* f_deg  = f_aggE + (size_t)N * EF;
        aggE = f_aggE; degf = f_deg;
        hipMemsetAsync(d_out, 0, (size_t)N * IN_F * sizeof(float), stream);
        hipMemsetAsync(d_ws, 0, (size_t)N * (EF + 1) * sizeof(float), stream);
        long long tot = (long long)E * IN_F;
        edge_scatter_kernel<<<(int)((tot + 255) / 256), 256, 0, stream>>>(H, ei, EA, out, f_aggE, f_deg, E);
    }

    node_mlp_kernel<<<(N + 31) / 32, 256, 0, stream>>>(out, aggE, degf, We, be, W1, b1, W2, b2, N);
}